// Round 1
// baseline (156.077 us; speedup 1.0000x reference)
//
#include <hip/hip_runtime.h>
#include <hip/hip_bf16.h>
#include <math.h>

#define T_ 16
#define B_ 16
#define N_ 256
#define H_ 512
#define L_ 64
#define K_ 8
#define SCALE 0.04419417382415922f   // THETA / sqrt(512)

// ---- DPP helpers: full-wave (64-lane) sum, result valid on lane 63 ----
template <int CTRL>
__device__ __forceinline__ float dpp_mov(float x) {
  return __int_as_float(
      __builtin_amdgcn_update_dpp(0, __float_as_int(x), CTRL, 0xF, 0xF, false));
}

__device__ __forceinline__ float wave_sum64_lane63(float v) {
  v += dpp_mov<0x111>(v);  // row_shr:1
  v += dpp_mov<0x112>(v);  // row_shr:2
  v += dpp_mov<0x114>(v);  // row_shr:4
  v += dpp_mov<0x118>(v);  // row_shr:8  -> lane15 of each 16-row has row sum
  v += dpp_mov<0x142>(v);  // row_bcast:15
  v += dpp_mov<0x143>(v);  // row_bcast:31 -> lane63 has full 64-lane sum
  return v;
}

// ============================================================================
// Kernel 1: one block per (b, n).  scores[t][b][n] = max_j  q[t,b,:] . k[n,b,j,:]
// Keys (512 MiB) are read exactly once, fully coalesced, no LDS staging.
// q fragments live in 128 VGPRs and are reused across all 16 j's per wave.
// ============================================================================
__global__ __launch_bounds__(256, 2) void score_kernel(
    const float* __restrict__ q, const float* __restrict__ keys,
    float* __restrict__ scores) {
  const int bid  = blockIdx.x;      // 0..4095
  const int n    = bid & (N_ - 1);  // consecutive blocks share b -> q hits L2
  const int b    = bid >> 8;
  const int tid  = threadIdx.x;
  const int wave = tid >> 6;
  const int lane = tid & 63;

  // Per-lane q fragments: q[i][4*lane .. +3] and q[i][256+4*lane .. +3]
  float4 qA[16], qB[16];
  const float* qb = q + (size_t)b * H_;  // + i*(B_*H_) + h
#pragma unroll
  for (int i = 0; i < 16; ++i) {
    qA[i] = *(const float4*)(qb + (size_t)i * (B_ * H_) + 4 * lane);
    qB[i] = *(const float4*)(qb + (size_t)i * (B_ * H_) + 256 + 4 * lane);
  }

  const float* kb = keys + (size_t)n * (B_ * L_ * H_) + (size_t)b * (L_ * H_);

  float smax[16];
#pragma unroll
  for (int i = 0; i < 16; ++i) smax[i] = -3.4e38f;

  // Each wave owns 16 of the 64 rows (j positions).
  for (int jj = 0; jj < 16; ++jj) {
    const int j = wave * 16 + jj;
    const float* kr = kb + j * H_;
    const float4 kA = *(const float4*)(kr + 4 * lane);        // 1KB coalesced
    const float4 kB = *(const float4*)(kr + 256 + 4 * lane);  // 1KB coalesced

#pragma unroll
    for (int i = 0; i < 16; ++i) {
      float a;
      a = kA.x * qA[i].x;
      a = fmaf(kA.y, qA[i].y, a);
      a = fmaf(kA.z, qA[i].z, a);
      a = fmaf(kA.w, qA[i].w, a);
      a = fmaf(kB.x, qB[i].x, a);
      a = fmaf(kB.y, qB[i].y, a);
      a = fmaf(kB.z, qB[i].z, a);
      a = fmaf(kB.w, qB[i].w, a);
      // sum a over all 64 lanes (h = 0..511); valid on lane 63 only
      const float s = wave_sum64_lane63(a);
      smax[i] = fmaxf(smax[i], s);  // only lane 63's value matters
    }
  }

  // Combine the 4 waves' per-j maxima.
  __shared__ float sm[4][16];
  if (lane == 63) {
#pragma unroll
    for (int i = 0; i < 16; ++i) sm[wave][i] = smax[i];
  }
  __syncthreads();
  if (tid < 16) {
    float v = sm[0][tid];
    v = fmaxf(v, sm[1][tid]);
    v = fmaxf(v, sm[2][tid]);
    v = fmaxf(v, sm[3][tid]);
    scores[(size_t)tid * (B_ * N_) + b * N_ + n] = v;  // (T,B,N)
  }
}

// ============================================================================
// Kernel 2: one wave per (t,b) row.  In-place softmax over N=256, then top-8
// with jax.lax.top_k semantics (value desc, index asc on ties).  Indices are
// written as float values (d_out is an fp32 buffer).
// ============================================================================
__global__ __launch_bounds__(256) void softmax_topk_kernel(
    float* __restrict__ att, float* __restrict__ out_idx) {
  const int row  = blockIdx.x * 4 + (threadIdx.x >> 6);  // t*B + b, 0..255
  const int lane = threadIdx.x & 63;

  float* s = att + (size_t)row * N_;
  const float4 v4 = *(const float4*)(s + 4 * lane);
  const float v[4] = {v4.x, v4.y, v4.z, v4.w};

  // max over row
  float m = fmaxf(fmaxf(v[0], v[1]), fmaxf(v[2], v[3]));
#pragma unroll
  for (int d = 1; d < 64; d <<= 1) m = fmaxf(m, __shfl_xor(m, d));

  float p[4];
#pragma unroll
  for (int e = 0; e < 4; ++e) p[e] = expf(SCALE * (v[e] - m));

  float sum = p[0] + p[1] + p[2] + p[3];
#pragma unroll
  for (int d = 1; d < 64; d <<= 1) sum += __shfl_xor(sum, d);
  const float inv = 1.0f / sum;

  float a[4];
#pragma unroll
  for (int e = 0; e < 4; ++e) a[e] = p[e] * inv;

  // write attention
  *(float4*)(s + 4 * lane) = make_float4(a[0], a[1], a[2], a[3]);

  // top-8: repeated argmax on a working copy
  float w[4] = {a[0], a[1], a[2], a[3]};
  for (int kk = 0; kk < K_; ++kk) {
    // local best among this lane's 4 (ascending n => strict > keeps low index)
    float bv = w[0];
    int bn = 4 * lane;
#pragma unroll
    for (int e = 1; e < 4; ++e) {
      if (w[e] > bv) { bv = w[e]; bn = 4 * lane + e; }
    }
    // wave argmax, tie -> smaller index
#pragma unroll
    for (int d = 1; d < 64; d <<= 1) {
      const float ov = __shfl_xor(bv, d);
      const int on = __shfl_xor(bn, d);
      if (ov > bv || (ov == bv && on < bn)) { bv = ov; bn = on; }
    }
    if (lane == 0) out_idx[kk * (T_ * B_) + row] = (float)bn;  // (k,T,B)
    // remove winner
#pragma unroll
    for (int e = 0; e < 4; ++e)
      if (4 * lane + e == bn) w[e] = -1.0f;
  }
}

extern "C" void kernel_launch(void* const* d_in, const int* in_sizes, int n_in,
                              void* d_out, int out_size, void* d_ws,
                              size_t ws_size, hipStream_t stream) {
  const float* q    = (const float*)d_in[0];   // (T,1,B,H) fp32
  const float* keys = (const float*)d_in[1];   // (N,B,L*H) fp32
  float* out = (float*)d_out;
  float* att = out;                 // 65536 floats, (T,B,N) raw scores -> attention
  float* idx = out + T_ * B_ * N_;  // 2048 floats, (k,T,B)

  score_kernel<<<B_ * N_, 256, 0, stream>>>(q, keys, att);
  softmax_topk_kernel<<<(T_ * B_) / 4, 256, 0, stream>>>(att, idx);
}